// Round 4
// baseline (220.864 us; speedup 1.0000x reference)
//
#include <hip/hip_runtime.h>
#include <math.h>

#define BB 8
#define NN 2048
#define FF 128
#define CH 128        // chunks per batch
#define CHSZ 16       // NN / CH

// ---------------------------------------------------------------------------
// Kernel 1: Wh[b,n,g] = sum_f h[b,n,f] * W[g,f];  s1 = Wh·a[:F], s2 = Wh·a[F:]
// block = 512 threads, 64 rows/block, per-thread tile 8g x 2r.
// ---------------------------------------------------------------------------
__global__ __launch_bounds__(512) void k1_wh(
        const float* __restrict__ h, const float* __restrict__ W,
        const float* __restrict__ a, float* __restrict__ Wh,
        float* __restrict__ s1, float* __restrict__ s2) {
    __shared__ __align__(16) float Wt[64][132];  // Wt[f_local][g], padded
    __shared__ float hs[64][65];                 // hs[r][f_local], padded
    const int tid = threadIdx.x;
    const int row0 = blockIdx.x * 64;            // global row = b*NN + i
    const int gq = tid & 15;                     // g = gq*8 .. gq*8+7
    const int rq = tid >> 4;                     // rows rq*2, rq*2+1

    float acc[2][8];
#pragma unroll
    for (int r = 0; r < 2; ++r)
#pragma unroll
        for (int g = 0; g < 8; ++g) acc[r][g] = 0.f;

    for (int half = 0; half < 2; ++half) {
        __syncthreads();
        for (int idx = tid; idx < 64 * 128; idx += 512) {
            int g = idx >> 6, fl = idx & 63;
            Wt[fl][g] = W[g * 128 + half * 64 + fl];
        }
        for (int idx = tid; idx < 64 * 64; idx += 512) {
            int r = idx >> 6, fl = idx & 63;
            hs[r][fl] = h[(row0 + r) * 128 + half * 64 + fl];
        }
        __syncthreads();
        for (int fl = 0; fl < 64; ++fl) {
            float4 w0 = *(const float4*)&Wt[fl][gq * 8];
            float4 w1 = *(const float4*)&Wt[fl][gq * 8 + 4];
            float h0 = hs[rq * 2 + 0][fl];
            float h1 = hs[rq * 2 + 1][fl];
            acc[0][0] += h0 * w0.x; acc[0][1] += h0 * w0.y;
            acc[0][2] += h0 * w0.z; acc[0][3] += h0 * w0.w;
            acc[0][4] += h0 * w1.x; acc[0][5] += h0 * w1.y;
            acc[0][6] += h0 * w1.z; acc[0][7] += h0 * w1.w;
            acc[1][0] += h1 * w0.x; acc[1][1] += h1 * w0.y;
            acc[1][2] += h1 * w0.z; acc[1][3] += h1 * w0.w;
            acc[1][4] += h1 * w1.x; acc[1][5] += h1 * w1.y;
            acc[1][6] += h1 * w1.z; acc[1][7] += h1 * w1.w;
        }
    }

    float a1v[8], a2v[8];
#pragma unroll
    for (int g = 0; g < 8; ++g) {
        a1v[g] = a[gq * 8 + g];
        a2v[g] = a[128 + gq * 8 + g];
    }
#pragma unroll
    for (int r = 0; r < 2; ++r) {
        int row = row0 + rq * 2 + r;
        *(float4*)&Wh[row * 128 + gq * 8] =
            make_float4(acc[r][0], acc[r][1], acc[r][2], acc[r][3]);
        *(float4*)&Wh[row * 128 + gq * 8 + 4] =
            make_float4(acc[r][4], acc[r][5], acc[r][6], acc[r][7]);
        float p1 = 0.f, p2 = 0.f;
#pragma unroll
        for (int g = 0; g < 8; ++g) {
            p1 += acc[r][g] * a1v[g];
            p2 += acc[r][g] * a2v[g];
        }
#pragma unroll
        for (int s = 1; s < 16; s <<= 1) {
            p1 += __shfl_xor(p1, s, 64);
            p2 += __shfl_xor(p2, s, 64);
        }
        if (gq == 0) { s1[row] = p1; s2[row] = p2; }
    }
}

// ---------------------------------------------------------------------------
// Kernel 2: split-k rank-by-count + exp. grid = B*32 blocks, 256 threads.
// Block stages the batch's 2048 keys, computes exact batch max M (every
// block gets the bitwise-identical M), ranks its 64 j's (wave w counts a
// disjoint 512-key range), scatters s2s/idxs/ps[rank]=exp(v-M).
// ---------------------------------------------------------------------------
__global__ __launch_bounds__(256) void k2_rank(
        const float* __restrict__ s2, float* __restrict__ s2s,
        int* __restrict__ idxs, float* __restrict__ ps) {
    __shared__ __align__(16) float ls[NN];
    __shared__ int part[4][64];
    __shared__ float wmax[4];
    const int t = threadIdx.x;
    const int blk = blockIdx.x;
    const int b = blk >> 5;              // 32 segs per batch
    const int seg = blk & 31;
    const int base = b * NN;
    float4* ls4 = (float4*)ls;
    const float4* g4 = (const float4*)(s2 + base);
    float m = -INFINITY;
    for (int i = t; i < NN / 4; i += 256) {
        float4 v4 = g4[i];
        ls4[i] = v4;
        m = fmaxf(m, fmaxf(fmaxf(v4.x, v4.y), fmaxf(v4.z, v4.w)));
    }
#pragma unroll
    for (int s = 1; s < 64; s <<= 1) m = fmaxf(m, __shfl_xor(m, s, 64));
    if ((t & 63) == 0) wmax[t >> 6] = m;
    __syncthreads();
    const float M = fmaxf(fmaxf(wmax[0], wmax[1]), fmaxf(wmax[2], wmax[3]));
    const int jj = t & 63;
    const int w  = t >> 6;
    const int j  = seg * 64 + jj;        // global j within batch
    const float v = ls[j];
    int rank = 0;
#pragma unroll 8
    for (int q = 0; q < 128; ++q) {
        float4 kv = ls4[w * 128 + q];    // wave-broadcast, conflict-free
        int kg = w * 512 + q * 4;
        rank += (kv.x < v) | ((kv.x == v) & (kg + 0 < j));
        rank += (kv.y < v) | ((kv.y == v) & (kg + 1 < j));
        rank += (kv.z < v) | ((kv.z == v) & (kg + 2 < j));
        rank += (kv.w < v) | ((kv.w == v) & (kg + 3 < j));
    }
    part[w][jj] = rank;
    __syncthreads();
    if (t < 64) {
        int r = part[0][t] + part[1][t] + part[2][t] + part[3][t];
        int jg = seg * 64 + t;
        float vv = ls[jg];
        s2s[base + r] = vv;
        idxs[base + r] = jg;
        ps[base + r] = expf(vv - M);
    }
}

// ---------------------------------------------------------------------------
// Kernel 3: per-chunk totals only (descending accumulation, same order as
// before): chunktot[f] = sum p*Wh, chunku[f] = sum Wh, chunkp = sum p.
// grid = B*CH blocks, 128 threads (f).
// ---------------------------------------------------------------------------
__global__ __launch_bounds__(128) void k3_chunk(
        const float* __restrict__ Wh, const int* __restrict__ idxs,
        const float* __restrict__ ps,
        float* __restrict__ chunktot, float* __restrict__ chunku,
        float* __restrict__ chunkp) {
    const int blk = blockIdx.x;
    const int b = blk >> 7, c = blk & 127;
    const int base = b * NN;
    const int f = threadIdx.x;
    float acc = 0.f, accu = 0.f, pacc = 0.f;
#pragma unroll
    for (int tt = CHSZ - 1; tt >= 0; --tt) {
        int r = c * CHSZ + tt;
        int jj = idxs[base + r];
        float pv = ps[base + r];
        float w = Wh[(base + jj) * 128 + f];
        acc += pv * w;
        accu += w;
        pacc += pv;
    }
    chunktot[(b * CH + c) * 128 + f] = acc;
    chunku[(b * CH + c) * 128 + f] = accu;
    if (f == 0) chunkp[b * CH + c] = pacc;
}

// ---------------------------------------------------------------------------
// Kernel 3b: exclusive suffix over chunk totals. Vector part staged in LDS
// (64 KB), per-f serial walk (conflict-free). Scalar p suffix via 7-step
// inclusive scan, exclusive taken as is[c+1]. Mean from chunku totals.
// ---------------------------------------------------------------------------
__global__ __launch_bounds__(128) void k3b_chunksuf(
        const float* __restrict__ chunktot, const float* __restrict__ chunku,
        const float* __restrict__ chunkp,
        float* __restrict__ chunksuf, float* __restrict__ chunkpsuf,
        float* __restrict__ meanv) {
    __shared__ float lt[CH][128];        // 64 KB
    __shared__ float lp[CH];
    const int b = blockIdx.x;
    const int f = threadIdx.x;
    float tu = 0.f;
#pragma unroll 4
    for (int c = 0; c < CH; ++c) {
        lt[c][f] = chunktot[(b * CH + c) * 128 + f];
        tu += chunku[(b * CH + c) * 128 + f];
    }
    lp[f] = chunkp[b * CH + f];          // thread f == chunk index
    __syncthreads();
    // inclusive suffix scan of lp (Hillis-Steele, in-place with barriers)
#pragma unroll
    for (int s = 1; s < CH; s <<= 1) {
        float add = (f + s < CH) ? lp[f + s] : 0.f;
        __syncthreads();
        lp[f] += add;
        __syncthreads();
    }
    chunkpsuf[b * CH + f] = (f < CH - 1) ? lp[f + 1] : 0.f;  // exclusive
    // vector exclusive suffix: thread f walks its LDS column
    float acc = 0.f;
#pragma unroll 4
    for (int c = CH - 1; c >= 0; --c) {
        chunksuf[(b * CH + c) * 128 + f] = acc;
        acc += lt[c][f];
    }
    meanv[b * 128 + f] = tu * (1.f / (float)NN);
}

// ---------------------------------------------------------------------------
// Kernel 4: per row binary search for threshold rank; tail (<=16 ranks)
// recomputed from Wh gathers (L2-hot) in the same descending order as the
// old `partial` array, then combined with chunk suffixes. ELU + store.
// ---------------------------------------------------------------------------
__global__ __launch_bounds__(256) void k4_out(
        const float* __restrict__ s1, const float* __restrict__ s2s,
        const int* __restrict__ idxs, const float* __restrict__ ps,
        const float* __restrict__ Wh,
        const float* __restrict__ chunksuf, const float* __restrict__ chunkpsuf,
        const float* __restrict__ meanv, float* __restrict__ out) {
    const int tid = threadIdx.x;
    const int rowg = blockIdx.x * 2 + (tid >> 7);
    const int f = tid & 127;
    const int b = rowg >> 11;           // / NN
    const int base = b * NN;
    const float s1v = s1[rowg];
    int lo = 0, hi = NN;
    while (lo < hi) {                    // exact fp32 predicate == reference
        int mid = (lo + hi) >> 1;
        if (s1v + s2s[base + mid] > 0.f) hi = mid; else lo = mid + 1;
    }
    float v;
    if (lo == NN) {
        v = meanv[b * 128 + f];          // all masked -> uniform softmax
    } else {
        const int c = lo >> 4;           // / CHSZ
        float tacc = 0.f, pacc = 0.f;
        for (int r = c * CHSZ + CHSZ - 1; r >= lo; --r) {
            float pv = ps[base + r];
            tacc += pv * Wh[(base + idxs[base + r]) * 128 + f];
            pacc += pv;
        }
        float num = tacc + chunksuf[(b * CH + c) * 128 + f];
        float den = pacc + chunkpsuf[b * CH + c];
        v = num / den;
    }
    out[rowg * 128 + f] = (v > 0.f) ? v : expm1f(v);
}

// ---------------------------------------------------------------------------
extern "C" void kernel_launch(void* const* d_in, const int* in_sizes, int n_in,
                              void* d_out, int out_size, void* d_ws, size_t ws_size,
                              hipStream_t stream) {
    (void)in_sizes; (void)n_in; (void)out_size; (void)ws_size;
    const float* h = (const float*)d_in[0];
    const float* W = (const float*)d_in[1];
    const float* a = (const float*)d_in[2];
    // d_in[3]=A1, d_in[4]=A2: dead code in the reference -> never read.
    float* out = (float*)d_out;

    float* Wh       = (float*)d_ws;          // B*N*F = 2,097,152
    float* s1       = Wh + 2097152;          // 16384
    float* s2       = s1 + 16384;
    float* s2s      = s2 + 16384;
    float* ps       = s2s + 16384;           // 16384
    int*   idxs     = (int*)(ps + 16384);    // 16384 ints
    float* chunktot = (float*)(idxs + 16384); // B*CH*F = 131072
    float* chunku   = chunktot + 131072;
    float* chunksuf = chunku + 131072;
    float* chunkp   = chunksuf + 131072;     // B*CH = 1024
    float* chunkpsuf= chunkp + 1024;         // 1024
    float* meanv    = chunkpsuf + 1024;      // 1024

    k1_wh<<<BB * NN / 64, 512, 0, stream>>>(h, W, a, Wh, s1, s2);
    k2_rank<<<BB * 32, 256, 0, stream>>>(s2, s2s, idxs, ps);
    k3_chunk<<<BB * CH, 128, 0, stream>>>(Wh, idxs, ps, chunktot, chunku, chunkp);
    k3b_chunksuf<<<BB, 128, 0, stream>>>(chunktot, chunku, chunkp,
                                         chunksuf, chunkpsuf, meanv);
    k4_out<<<BB * NN / 2, 256, 0, stream>>>(s1, s2s, idxs, ps, Wh,
                                            chunksuf, chunkpsuf, meanv, out);
}

// Round 5
// 195.516 us; speedup vs baseline: 1.1296x; 1.1296x over previous
//
#include <hip/hip_runtime.h>
#include <math.h>

#define BB 8
#define NN 2048
#define FF 128
#define CH 128        // chunks per batch
#define CHSZ 16       // NN / CH

// ---------------------------------------------------------------------------
// Kernel 1: Wh[b,n,g] = sum_f h[b,n,f] * W[g,f];  s1 = Wh·a[:F], s2 = Wh·a[F:]
// block = 512 threads, 64 rows/block, per-thread tile 8g x 2r.
// ---------------------------------------------------------------------------
__global__ __launch_bounds__(512) void k1_wh(
        const float* __restrict__ h, const float* __restrict__ W,
        const float* __restrict__ a, float* __restrict__ Wh,
        float* __restrict__ s1, float* __restrict__ s2) {
    __shared__ __align__(16) float Wt[64][132];  // Wt[f_local][g], padded
    __shared__ float hs[64][65];                 // hs[r][f_local], padded
    const int tid = threadIdx.x;
    const int row0 = blockIdx.x * 64;            // global row = b*NN + i
    const int gq = tid & 15;                     // g = gq*8 .. gq*8+7
    const int rq = tid >> 4;                     // rows rq*2, rq*2+1

    float acc[2][8];
#pragma unroll
    for (int r = 0; r < 2; ++r)
#pragma unroll
        for (int g = 0; g < 8; ++g) acc[r][g] = 0.f;

    for (int half = 0; half < 2; ++half) {
        __syncthreads();
        for (int idx = tid; idx < 64 * 128; idx += 512) {
            int g = idx >> 6, fl = idx & 63;
            Wt[fl][g] = W[g * 128 + half * 64 + fl];
        }
        for (int idx = tid; idx < 64 * 64; idx += 512) {
            int r = idx >> 6, fl = idx & 63;
            hs[r][fl] = h[(row0 + r) * 128 + half * 64 + fl];
        }
        __syncthreads();
        for (int fl = 0; fl < 64; ++fl) {
            float4 w0 = *(const float4*)&Wt[fl][gq * 8];
            float4 w1 = *(const float4*)&Wt[fl][gq * 8 + 4];
            float h0 = hs[rq * 2 + 0][fl];
            float h1 = hs[rq * 2 + 1][fl];
            acc[0][0] += h0 * w0.x; acc[0][1] += h0 * w0.y;
            acc[0][2] += h0 * w0.z; acc[0][3] += h0 * w0.w;
            acc[0][4] += h0 * w1.x; acc[0][5] += h0 * w1.y;
            acc[0][6] += h0 * w1.z; acc[0][7] += h0 * w1.w;
            acc[1][0] += h1 * w0.x; acc[1][1] += h1 * w0.y;
            acc[1][2] += h1 * w0.z; acc[1][3] += h1 * w0.w;
            acc[1][4] += h1 * w1.x; acc[1][5] += h1 * w1.y;
            acc[1][6] += h1 * w1.z; acc[1][7] += h1 * w1.w;
        }
    }

    float a1v[8], a2v[8];
#pragma unroll
    for (int g = 0; g < 8; ++g) {
        a1v[g] = a[gq * 8 + g];
        a2v[g] = a[128 + gq * 8 + g];
    }
#pragma unroll
    for (int r = 0; r < 2; ++r) {
        int row = row0 + rq * 2 + r;
        *(float4*)&Wh[row * 128 + gq * 8] =
            make_float4(acc[r][0], acc[r][1], acc[r][2], acc[r][3]);
        *(float4*)&Wh[row * 128 + gq * 8 + 4] =
            make_float4(acc[r][4], acc[r][5], acc[r][6], acc[r][7]);
        float p1 = 0.f, p2 = 0.f;
#pragma unroll
        for (int g = 0; g < 8; ++g) {
            p1 += acc[r][g] * a1v[g];
            p2 += acc[r][g] * a2v[g];
        }
#pragma unroll
        for (int s = 1; s < 16; s <<= 1) {
            p1 += __shfl_xor(p1, s, 64);
            p2 += __shfl_xor(p2, s, 64);
        }
        if (gq == 0) { s1[row] = p1; s2[row] = p2; }
    }
}

// ---------------------------------------------------------------------------
// Kernel 2: split-k rank-by-count + exp + threshold count. grid = B*32
// blocks, 256 threads. Block stages the batch's 2048 keys in LDS, computes
// exact batch max M, and for its 64 j's computes BOTH:
//   rank[j] = #{k: s2_k < v or (s2_k==v and k<j)}   (stable sort position)
//   lo[j]   = #{k: s1_j + s2_k <= 0}                (first passing rank —
//             fp32 '+' is monotone, so count == lower bound in sorted order)
// Scatters idxs/ps[rank]; writes lo per row. No dependent global chains.
// ---------------------------------------------------------------------------
__global__ __launch_bounds__(256) void k2_rank(
        const float* __restrict__ s2, const float* __restrict__ s1,
        int* __restrict__ idxs, float* __restrict__ ps,
        int* __restrict__ lo_arr) {
    __shared__ __align__(16) float ls[NN];
    __shared__ int part[4][64];
    __shared__ int lpart[4][64];
    __shared__ float wmax[4];
    const int t = threadIdx.x;
    const int blk = blockIdx.x;
    const int b = blk >> 5;              // 32 segs per batch
    const int seg = blk & 31;
    const int base = b * NN;
    float4* ls4 = (float4*)ls;
    const float4* g4 = (const float4*)(s2 + base);
    float m = -INFINITY;
    for (int i = t; i < NN / 4; i += 256) {
        float4 v4 = g4[i];
        ls4[i] = v4;
        m = fmaxf(m, fmaxf(fmaxf(v4.x, v4.y), fmaxf(v4.z, v4.w)));
    }
#pragma unroll
    for (int s = 1; s < 64; s <<= 1) m = fmaxf(m, __shfl_xor(m, s, 64));
    if ((t & 63) == 0) wmax[t >> 6] = m;
    __syncthreads();
    const float M = fmaxf(fmaxf(wmax[0], wmax[1]), fmaxf(wmax[2], wmax[3]));
    const int jj = t & 63;
    const int w  = t >> 6;
    const int j  = seg * 64 + jj;        // global j within batch
    const float v = ls[j];
    const float s1v = s1[base + j];
    int rank = 0, cnt = 0;
#pragma unroll 8
    for (int q = 0; q < 128; ++q) {
        float4 kv = ls4[w * 128 + q];    // wave-broadcast, conflict-free
        int kg = w * 512 + q * 4;
        rank += (kv.x < v) | ((kv.x == v) & (kg + 0 < j));
        rank += (kv.y < v) | ((kv.y == v) & (kg + 1 < j));
        rank += (kv.z < v) | ((kv.z == v) & (kg + 2 < j));
        rank += (kv.w < v) | ((kv.w == v) & (kg + 3 < j));
        cnt += (s1v + kv.x <= 0.f);
        cnt += (s1v + kv.y <= 0.f);
        cnt += (s1v + kv.z <= 0.f);
        cnt += (s1v + kv.w <= 0.f);
    }
    part[w][jj] = rank;
    lpart[w][jj] = cnt;
    __syncthreads();
    if (t < 64) {
        int r = part[0][t] + part[1][t] + part[2][t] + part[3][t];
        int jg = seg * 64 + t;
        float vv = ls[jg];
        idxs[base + r] = jg;
        ps[base + r] = expf(vv - M);
        lo_arr[base + jg] = lpart[0][t] + lpart[1][t] + lpart[2][t] + lpart[3][t];
    }
}

// ---------------------------------------------------------------------------
// Kernel 3: within-chunk inclusive suffix of p[r]*Wh[idx[r],:] (-> partial),
// p[r] (-> psuf, f==0), plus chunk totals and unweighted sums (for mean).
// grid = B*CH blocks, 128 threads (f). Descending accumulation order.
// ---------------------------------------------------------------------------
__global__ __launch_bounds__(128) void k3_scan(
        const float* __restrict__ Wh, const int* __restrict__ idxs,
        const float* __restrict__ ps,
        float* __restrict__ partial, float* __restrict__ psuf,
        float* __restrict__ chunktot, float* __restrict__ chunku,
        float* __restrict__ chunkp) {
    const int blk = blockIdx.x;
    const int b = blk >> 7, c = blk & 127;
    const int base = b * NN;
    const int f = threadIdx.x;
    float acc = 0.f, accu = 0.f, pacc = 0.f;
#pragma unroll
    for (int tt = CHSZ - 1; tt >= 0; --tt) {
        int r = c * CHSZ + tt;
        int jj = idxs[base + r];
        float pv = ps[base + r];
        float w = Wh[(base + jj) * 128 + f];
        acc += pv * w;
        accu += w;
        pacc += pv;
        partial[(base + r) * 128 + f] = acc;
        if (f == 0) psuf[base + r] = pacc;
    }
    chunktot[(b * CH + c) * 128 + f] = acc;
    chunku[(b * CH + c) * 128 + f] = accu;
    if (f == 0) chunkp[b * CH + c] = pacc;
}

// ---------------------------------------------------------------------------
// Kernel 3b: exclusive suffix over chunk totals. Vector part staged in LDS
// (64 KB), per-f serial walk (conflict-free). Scalar p suffix via 7-step
// scan; exclusive = inclusive[c+1]. Mean from chunku totals.
// ---------------------------------------------------------------------------
__global__ __launch_bounds__(128) void k3b_chunksuf(
        const float* __restrict__ chunktot, const float* __restrict__ chunku,
        const float* __restrict__ chunkp,
        float* __restrict__ chunksuf, float* __restrict__ chunkpsuf,
        float* __restrict__ meanv) {
    __shared__ float lt[CH][128];        // 64 KB
    __shared__ float lp[CH];
    const int b = blockIdx.x;
    const int f = threadIdx.x;
    float tu = 0.f;
#pragma unroll 4
    for (int c = 0; c < CH; ++c) {
        lt[c][f] = chunktot[(b * CH + c) * 128 + f];
        tu += chunku[(b * CH + c) * 128 + f];
    }
    lp[f] = chunkp[b * CH + f];          // thread f == chunk index
    __syncthreads();
#pragma unroll
    for (int s = 1; s < CH; s <<= 1) {
        float add = (f + s < CH) ? lp[f + s] : 0.f;
        __syncthreads();
        lp[f] += add;
        __syncthreads();
    }
    chunkpsuf[b * CH + f] = (f < CH - 1) ? lp[f + 1] : 0.f;  // exclusive
    float acc = 0.f;
#pragma unroll 4
    for (int c = CH - 1; c >= 0; --c) {
        chunksuf[(b * CH + c) * 128 + f] = acc;
        acc += lt[c][f];
    }
    meanv[b * 128 + f] = tu * (1.f / (float)NN);
}

// ---------------------------------------------------------------------------
// Kernel 4: pure combine — no search, no gather loops. Per row: read lo,
// fetch partial[lo] + chunksuf[c] (float4), den = psuf[lo] + chunkpsuf[c],
// divide, ELU, store. block = 256 thr = 8 rows x 32 lanes x float4.
// ---------------------------------------------------------------------------
__global__ __launch_bounds__(256) void k4_out(
        const int* __restrict__ lo_arr, const float* __restrict__ psuf,
        const float* __restrict__ chunkpsuf, const float* __restrict__ partial,
        const float* __restrict__ chunksuf, const float* __restrict__ meanv,
        float* __restrict__ out) {
    const int tid = threadIdx.x;
    const int rowg = blockIdx.x * 8 + (tid >> 5);
    const int fq = (tid & 31) * 4;
    const int b = rowg >> 11;           // / NN
    const int base = b * NN;
    const int lo = lo_arr[rowg];
    float4 v;
    if (lo == NN) {
        v = *(const float4*)&meanv[b * 128 + fq];   // all masked -> uniform
    } else {
        const int c = lo >> 4;          // / CHSZ
        float4 pp = *(const float4*)&partial[(base + lo) * 128 + fq];
        float4 cs = *(const float4*)&chunksuf[(b * CH + c) * 128 + fq];
        float den = psuf[base + lo] + chunkpsuf[b * CH + c];
        v.x = (pp.x + cs.x) / den;
        v.y = (pp.y + cs.y) / den;
        v.z = (pp.z + cs.z) / den;
        v.w = (pp.w + cs.w) / den;
    }
    v.x = (v.x > 0.f) ? v.x : expm1f(v.x);
    v.y = (v.y > 0.f) ? v.y : expm1f(v.y);
    v.z = (v.z > 0.f) ? v.z : expm1f(v.z);
    v.w = (v.w > 0.f) ? v.w : expm1f(v.w);
    *(float4*)&out[rowg * 128 + fq] = v;
}

// ---------------------------------------------------------------------------
extern "C" void kernel_launch(void* const* d_in, const int* in_sizes, int n_in,
                              void* d_out, int out_size, void* d_ws, size_t ws_size,
                              hipStream_t stream) {
    (void)in_sizes; (void)n_in; (void)out_size; (void)ws_size;
    const float* h = (const float*)d_in[0];
    const float* W = (const float*)d_in[1];
    const float* a = (const float*)d_in[2];
    // d_in[3]=A1, d_in[4]=A2: dead code in the reference -> never read.
    float* out = (float*)d_out;

    float* Wh       = (float*)d_ws;          // B*N*F = 2,097,152
    float* partial  = Wh + 2097152;          // B*N*F = 2,097,152
    float* s1       = partial + 2097152;     // 16384
    float* s2       = s1 + 16384;
    float* ps       = s2 + 16384;            // 16384
    float* psuf     = ps + 16384;            // 16384
    int*   idxs     = (int*)(psuf + 16384);  // 16384 ints
    int*   lo_arr   = idxs + 16384;          // 16384 ints
    float* chunktot = (float*)(lo_arr + 16384); // B*CH*F = 131072
    float* chunku   = chunktot + 131072;
    float* chunksuf = chunku + 131072;
    float* chunkp   = chunksuf + 131072;     // B*CH = 1024
    float* chunkpsuf= chunkp + 1024;         // 1024
    float* meanv    = chunkpsuf + 1024;      // 1024

    k1_wh<<<BB * NN / 64, 512, 0, stream>>>(h, W, a, Wh, s1, s2);
    k2_rank<<<BB * 32, 256, 0, stream>>>(s2, s1, idxs, ps, lo_arr);
    k3_scan<<<BB * CH, 128, 0, stream>>>(Wh, idxs, ps, partial, psuf,
                                         chunktot, chunku, chunkp);
    k3b_chunksuf<<<BB, 128, 0, stream>>>(chunktot, chunku, chunkp,
                                         chunksuf, chunkpsuf, meanv);
    k4_out<<<BB * NN / 8, 256, 0, stream>>>(lo_arr, psuf, chunkpsuf,
                                            partial, chunksuf, meanv, out);
}